// Round 1
// baseline (94.004 us; speedup 1.0000x reference)
//
#include <hip/hip_runtime.h>

// AdderDeconv_77034533421671
//
// Algebraic collapse: adder_deconv output = -sum|x-w| <= 0 everywhere (exact
// in fp32). Each block applies relu BEFORE bn, so relu(adder_out) == 0
// exactly, bn(0) == beta - mean*inv (per-channel constant), and unpool only
// scatters <=0 values into zeros (relu also kills those). Hence the final
// output depends ONLY on w1b (d_in[6]) and bn1 row 1 (d_in[15..18]):
//
//   out[b,co,h,w] = -sum_ci sum_k ( tap(h,w,k) valid ? |c[ci]-w1b[co,ci,k]|
//                                                    : |w1b[co,ci,k]| )
//   c[ci] = beta - mean * (gamma * rsqrt(var + 1e-5)),  row 1 of bn1 params.
//
// Only 27 distinct output values: 3 channels x 9 border classes (corner /
// edge / interior of the 3x3, pad=1 footprint at 112x112). Output is
// batch-independent. Each block recomputes the 27 values (trivial) and
// writes its float4 slice of the 4*3*112*112 output.

__global__ __launch_bounds__(256)
void adder_collapse_kernel(const float* __restrict__ w1b,   // [3,32,3,3]
                           const float* __restrict__ bg,    // bn1_gamma [2,32]
                           const float* __restrict__ bb,    // bn1_beta  [2,32]
                           const float* __restrict__ bm,    // bn1_mean  [2,32]
                           const float* __restrict__ bv,    // bn1_var   [2,32]
                           float* __restrict__ out)         // [4,3,112,112]
{
    __shared__ float c[32];      // bn1[1] constant per input channel
    __shared__ float D[2][27];   // [0]=sum|w| (pad tap), [1]=sum|c-w| ; idx co*9+k
    __shared__ float cls[27];    // final value per (co, border-class)

    const int t = threadIdx.x;

    // phase 0: bn constants for row 1 of bn1 params
    if (t < 32) {
        const float inv = bg[32 + t] * rsqrtf(bv[32 + t] + 1e-5f);
        c[t] = bb[32 + t] - bm[32 + t] * inv;
    }
    __syncthreads();

    // phase 1: per-tap channel sums
    if (t < 54) {
        const int which = t / 27;          // 0 -> |w| , 1 -> |c - w|
        const int j     = t % 27;          // co*9 + k
        const int co    = j / 9;
        const int k     = j % 9;
        float s = 0.0f;
        #pragma unroll
        for (int ci = 0; ci < 32; ++ci) {
            const float w = w1b[(co * 32 + ci) * 9 + k];
            s += fabsf(which ? (c[ci] - w) : w);
        }
        D[which][j] = s;
    }
    __syncthreads();

    // phase 2: 27 class values.  Tap (ky,kx) at output (h,w) is in-bounds iff
    // h+ky-1 in [0,111] and w+kx-1 in [0,111].  Row class rc: 0 (h==0),
    // 2 (h==111), 1 otherwise; col class cc likewise.
    if (t < 27) {
        const int co = t / 9;
        const int cl = t % 9;
        const int rc = cl / 3;
        const int cc = cl % 3;
        float s = 0.0f;
        #pragma unroll
        for (int ky = 0; ky < 3; ++ky) {
            #pragma unroll
            for (int kx = 0; kx < 3; ++kx) {
                const bool vy = !((rc == 0 && ky == 0) || (rc == 2 && ky == 2));
                const bool vx = !((cc == 0 && kx == 0) || (cc == 2 && kx == 2));
                const int  k  = ky * 3 + kx;
                s += (vy && vx) ? D[1][co * 9 + k] : D[0][co * 9 + k];
            }
        }
        cls[t] = -s;
    }
    __syncthreads();

    // phase 3: broadcast write.  150528 floats = 37632 float4 = 147 * 256.
    // Row of 112 = 28 float4s; within a float4 only the very first (w==0) and
    // very last (w==111) element of a row can be an edge column class.
    const int idx4 = blockIdx.x * 256 + t;     // 0..37631
    const int q    = idx4 % 28;                // float4 within row
    const int r    = idx4 / 28;                // 0..(4*3*112-1)
    const int h    = r % 112;
    const int co   = (r / 112) % 3;            // batch index is irrelevant
    const int rc   = (h == 0) ? 0 : ((h == 111) ? 2 : 1);
    const int base = co * 9 + rc * 3;

    const float mid = cls[base + 1];
    float4 v;
    v.x = (q == 0)  ? cls[base + 0] : mid;
    v.y = mid;
    v.z = mid;
    v.w = (q == 27) ? cls[base + 2] : mid;

    reinterpret_cast<float4*>(out)[idx4] = v;
}

extern "C" void kernel_launch(void* const* d_in, const int* in_sizes, int n_in,
                              void* d_out, int out_size, void* d_ws, size_t ws_size,
                              hipStream_t stream)
{
    const float* w1b = (const float*)d_in[6];    // [3,32,3,3]
    const float* bg  = (const float*)d_in[15];   // bn1_gamma [2,32]
    const float* bb  = (const float*)d_in[16];   // bn1_beta
    const float* bm  = (const float*)d_in[17];   // bn1_mean
    const float* bv  = (const float*)d_in[18];   // bn1_var

    // 4*3*112*112 = 150528 floats = 37632 float4 = 147 blocks * 256 threads
    adder_collapse_kernel<<<147, 256, 0, stream>>>(
        w1b, bg, bb, bm, bv, (float*)d_out);
}